// Round 4
// baseline (153.287 us; speedup 1.0000x reference)
//
#include <hip/hip_runtime.h>
#include <math.h>

// pred (8,4,256,256) f32, target (8,256,256) i32, w (8,1,256,256) f32 -> scalar.
constexpr int B = 8;
constexpr int C = 4;
constexpr int H = 256;
constexpr int W = 256;
constexpr int NC = C - 1;          // classes 1..3
constexpr int NIMG = B * NC;       // 24
constexpr float EDT_INF = 1e10f;   // matches reference INF
constexpr float LOSS_SCALE = 1.0f / (float)(NC * B * H * W);
constexpr int BIGI = 1 << 20;

// ---------------------------------------------------------------------------
// K1: per-(img,row) 1D nearest-site distance along j via ballot bit-scans.
// block = (img, i), 256 threads = j. Stores ROW-MAJOR g[img][i][j] (squared,
// EDT_INF if row has no site) -> both load and store fully coalesced, no LDS
// transpose needed (K2 consumes rows with threads = j).
// ---------------------------------------------------------------------------
__global__ __launch_bounds__(256) void rowscan_kernel(
        const int* __restrict__ target,
        float* __restrict__ g_m, float* __restrict__ g_nm) {
    const int img = blockIdx.x >> 8;
    const int i   = blockIdx.x & (H - 1);
    const int b   = img / NC;
    const int c   = img - b * NC + 1;
    const int j   = threadIdx.x;
    const int lane = j & 63, wid = j >> 6, wbase = wid << 6;

    const int tv = target[(b * H + i) * W + j];
    const bool m = (tv == c);
    const unsigned long long bm = __ballot(m);
    const unsigned long long bn = ~bm;   // block fully active: complement valid

    __shared__ int wlast[2][4];   // highest site j in wave (or -BIGI)
    __shared__ int wfirst[2][4];  // lowest  site j in wave (or +BIGI)
    if (lane == 0) {
        wlast [0][wid] = bm ? (wbase + 63 - __clzll(bm)) : -BIGI;
        wfirst[0][wid] = bm ? (wbase + (int)__ffsll(bm) - 1) : BIGI;
        wlast [1][wid] = bn ? (wbase + 63 - __clzll(bn)) : -BIGI;
        wfirst[1][wid] = bn ? (wbase + (int)__ffsll(bn) - 1) : BIGI;
    }
    __syncthreads();

    const size_t ridx = ((size_t)img * H + i) * W + j;

    #pragma unroll
    for (int sel = 0; sel < 2; ++sel) {
        const unsigned long long bb = sel ? bn : bm;
        // nearest site at index <= j
        const unsigned long long below = bb << (63 - lane);
        int last = -BIGI;
        #pragma unroll
        for (int w = 0; w < 3; ++w) if (w < wid) last = max(last, wlast[sel][w]);
        if (below) last = j - __clzll(below);
        // nearest site at index >= j
        const unsigned long long above = bb >> lane;
        int nxt = BIGI;
        #pragma unroll
        for (int w = 1; w < 4; ++w) if (w > wid) nxt = min(nxt, wfirst[sel][w]);
        if (above) nxt = j + (int)__ffsll(above) - 1;

        const int fm = min(j - last, nxt - j);
        const float g = (fm <= 255) ? (float)(fm * fm) : EDT_INF;
        if (sel == 0) g_m[ridx] = g; else g_nm[ridx] = g;
    }
}

// ---------------------------------------------------------------------------
// K2: column-direction envelope with exact early-exit outward scan + fused
// loss. block = (img, i), 256 threads = j -> ALL global accesses coalesced.
// Per pixel only the opposite-set distance is nonzero (own-set term == 0).
// Outward scan is exact: any candidate at |ip-i| = d contributes >= d^2, so
// once d^2 >= best no farther row can improve. Random 25%-density masks
// terminate in ~3-6 wave-iterations. Degenerate mask -> best stays ~1e10
// -> dist forced to 0 (matches reference's degenerate-zero semantics).
// ---------------------------------------------------------------------------
__global__ __launch_bounds__(256) void envelope_loss_kernel(
        const float* __restrict__ pred,
        const int* __restrict__ target,
        const float* __restrict__ wmap,
        const float* __restrict__ g_m,
        const float* __restrict__ g_nm,
        float* __restrict__ out) {
    const int img = blockIdx.x >> 8;
    const int i   = blockIdx.x & (H - 1);
    const int b   = img / NC;
    const int c   = img - b * NC + 1;
    const int j   = threadIdx.x;

    const int pix = (b * H + i) * W + j;
    const int tv  = target[pix];
    const bool in_c = (tv == c);

    // pixel in class c -> needs edt(~m); else edt(m).
    const float* gp = (in_c ? g_nm : g_m) + (size_t)img * H * W + j;

    float best = gp[(size_t)i * W];          // d = 0 candidate
    for (int d = 1; d < H; ++d) {
        const float dd = (float)(d * d);
        if (!__any(dd < best)) break;        // wave-uniform exit
        if (dd < best) {
            const int lo = i - d;
            if (lo >= 0) best = fminf(best, gp[(size_t)lo * W] + dd);
            const int hi = i + d;
            if (hi < H) best = fminf(best, gp[(size_t)hi * W] + dd);
        }
    }
    const float dist = (best < 1e9f) ? sqrtf(best) : 0.0f;

    // fused loss: |softmax_c - t_c| * w * dist   (all loads coalesced)
    const float tc = in_c ? 1.0f : 0.0f;
    const float wv = wmap[pix];
    const float* pp = pred + ((size_t)b * C * H + i) * W + j;
    const float p0 = pp[0];
    const float p1 = pp[(size_t)H * W];
    const float p2 = pp[2 * (size_t)H * W];
    const float p3 = pp[3 * (size_t)H * W];
    const float mx = fmaxf(fmaxf(p0, p1), fmaxf(p2, p3));
    const float e0 = __expf(p0 - mx);
    const float e1 = __expf(p1 - mx);
    const float e2 = __expf(p2 - mx);
    const float e3 = __expf(p3 - mx);
    const float inv = 1.0f / (e0 + e1 + e2 + e3);
    const float pc = ((c == 1) ? e1 : (c == 2) ? e2 : e3) * inv;
    float v = fabsf(pc - tc) * wv * dist;

    // block reduction: wave shuffle + LDS across 4 waves, one atomic per block
    for (int off = 32; off > 0; off >>= 1) v += __shfl_down(v, off, 64);
    __shared__ float swave[4];
    const int lane = j & 63, wid = j >> 6;
    if (lane == 0) swave[wid] = v;
    __syncthreads();
    if (j == 0) {
        const float s = swave[0] + swave[1] + swave[2] + swave[3];
        atomicAdd(out, s * LOSS_SCALE);
    }
}

// ---------------------------------------------------------------------------
extern "C" void kernel_launch(void* const* d_in, const int* in_sizes, int n_in,
                              void* d_out, int out_size, void* d_ws, size_t ws_size,
                              hipStream_t stream) {
    const float* pred   = (const float*)d_in[0];
    const int*   target = (const int*)d_in[1];
    const float* wmap   = (const float*)d_in[2];
    float* out = (float*)d_out;

    float* g_m  = (float*)d_ws;
    float* g_nm = g_m + (size_t)NIMG * H * W;

    hipMemsetAsync(out, 0, sizeof(float), stream);
    rowscan_kernel<<<NIMG * H, 256, 0, stream>>>(target, g_m, g_nm);
    envelope_loss_kernel<<<NIMG * H, 256, 0, stream>>>(pred, target, wmap,
                                                       g_m, g_nm, out);
}